// Round 9
// baseline (961.669 us; speedup 1.0000x reference)
//
#include <hip/hip_runtime.h>
#include <hip/hip_bf16.h>
#include <cstdint>
#include <cstddef>

// Problem constants
#define T_TOK 8192          // B*S tokens
#define H_DIM 1024
#define I_DIM 4096
#define E_NUM 8
#define NSLOT (T_TOK*2)
#define ROUTER_BLOCKS 512
#define MAXBLK 144          // >= sum ceil(cnt_e/128) worst case (136)

// Workspace layout (byte offsets), total 273 MB.
#define OFF_CNT     0
#define OFF_NBLK    128
#define OFF_BLKE    256
#define OFF_BLKRB   1024
#define OFF_PSUM    2048            // 512*8*4 = 16 KB
#define OFF_GATE    32768           // NSLOT float = 64 KB
#define OFF_ROWMAP  131072          // E*T_TOK int = 256 KB
#define OFF_XB      (1ull<<20)      // 16 MB  bf16 x
#define OFF_WB1     (17ull<<20)     // 64 MB  bf16 W1
#define OFF_WB2     (81ull<<20)     // 64 MB  bf16 W2
#define OFF_HID     (145ull<<20)    // 128 MB bf16 hidden

typedef __attribute__((ext_vector_type(8))) short bf16x8;
typedef __attribute__((ext_vector_type(4))) float f32x4;

__device__ __forceinline__ void gll16(const void* g, void* l) {
    __builtin_amdgcn_global_load_lds((const __attribute__((address_space(1))) void*)g,
                                     (__attribute__((address_space(3))) void*)l, 16, 0, 0);
}

__device__ __forceinline__ ushort f2bf(float f) {   // RNE, finite inputs
    uint32_t u = __float_as_uint(f);
    return (ushort)((u + 0x7FFFu + ((u >> 16) & 1u)) >> 16);
}

__global__ void init_kernel(int* __restrict__ cnt) {
    if (threadIdx.x < E_NUM) cnt[threadIdx.x] = 0;
}

// fp32 -> bf16 bulk conversion (weights), float4 in / ushort4 out, grid-stride.
__global__ __launch_bounds__(256) void f2bf_kernel(const float* __restrict__ s,
                                                   ushort* __restrict__ d, int n4) {
    for (int i = blockIdx.x * 256 + threadIdx.x; i < n4; i += gridDim.x * 256) {
        const float4 v = ((const float4*)s)[i];
        ushort4 o;
        o.x = f2bf(v.x); o.y = f2bf(v.y); o.z = f2bf(v.z); o.w = f2bf(v.w);
        ((ushort4*)d)[i] = o;
    }
}

__global__ __launch_bounds__(256) void zero_out_kernel(float* __restrict__ out) {
    const int i = blockIdx.x * 256 + threadIdx.x;     // over T*H/4
    ((float4*)out)[i] = make_float4(0.f, 0.f, 0.f, 0.f);
}

// fp32 router + fused x->bf16 conversion. One wave per token-quad.
__global__ __launch_bounds__(256) void router_kernel(
    const float* __restrict__ x, const float* __restrict__ Wr,
    int* __restrict__ cnt, float* __restrict__ psum_part,
    float* __restrict__ gate, int* __restrict__ rowmap,
    ushort* __restrict__ xb)
{
    __shared__ float ps[E_NUM];
    __shared__ int   lcnt[E_NUM];
    __shared__ int   lbase[E_NUM];
    const int tid  = threadIdx.x;
    const int lane = tid & 63;
    const int wid  = tid >> 6;
    if (tid < E_NUM) { ps[tid] = 0.0f; lcnt[tid] = 0; }
    __syncthreads();

    int   e_idx[4][2];
    int   e_pos[4][2];
    float e_w[4][2];

#pragma unroll
    for (int it = 0; it < 4; ++it) {
        const int t = blockIdx.x * 16 + wid * 4 + it;
        const float* xr = x + (size_t)t * H_DIM;
        float xv[16];
#pragma unroll
        for (int j = 0; j < 16; ++j) xv[j] = xr[lane + j * 64];
        // fused bf16 conversion of x
#pragma unroll
        for (int j = 0; j < 16; ++j) xb[(size_t)t * H_DIM + lane + j * 64] = f2bf(xv[j]);
        float l[E_NUM];
#pragma unroll
        for (int e = 0; e < E_NUM; ++e) {
            const float* wr = Wr + e * H_DIM;
            float s = 0.0f;
#pragma unroll
            for (int j = 0; j < 16; ++j) s += xv[j] * wr[lane + j * 64];
#pragma unroll
            for (int off = 32; off > 0; off >>= 1) s += __shfl_xor(s, off, 64);
            l[e] = s;
        }
        float m = l[0];
#pragma unroll
        for (int e = 1; e < E_NUM; ++e) m = fmaxf(m, l[e]);
        float p[E_NUM], sum = 0.0f;
#pragma unroll
        for (int e = 0; e < E_NUM; ++e) { p[e] = expf(l[e] - m); sum += p[e]; }
        const float inv = 1.0f / sum;
#pragma unroll
        for (int e = 0; e < E_NUM; ++e) p[e] *= inv;
        int i0 = 0;
#pragma unroll
        for (int e = 1; e < E_NUM; ++e) if (p[e] > p[i0]) i0 = e;
        int i1 = (i0 == 0) ? 1 : 0;
#pragma unroll
        for (int e = 0; e < E_NUM; ++e) if (e != i0 && p[e] > p[i1]) i1 = e;
        const float s2 = p[i0] + p[i1];

        if (lane == 0) {
            e_idx[it][0] = i0; e_idx[it][1] = i1;
            e_w[it][0] = p[i0] / s2; e_w[it][1] = p[i1] / s2;
            e_pos[it][0] = atomicAdd(&lcnt[i0], 1);
            e_pos[it][1] = atomicAdd(&lcnt[i1], 1);
#pragma unroll
            for (int e = 0; e < E_NUM; ++e) atomicAdd(&ps[e], p[e]);
        }
    }
    __syncthreads();
    if (tid < E_NUM) {
        lbase[tid] = atomicAdd(&cnt[tid], lcnt[tid]);
        psum_part[blockIdx.x * E_NUM + tid] = ps[tid];
    }
    __syncthreads();
    if (lane == 0) {
#pragma unroll
        for (int it = 0; it < 4; ++it) {
            const int t = blockIdx.x * 16 + wid * 4 + it;
#pragma unroll
            for (int k = 0; k < 2; ++k) {
                const int e = e_idx[it][k];
                const int pos = lbase[e] + e_pos[it][k];
                rowmap[e * T_TOK + pos] = 2 * t + k;
                gate[2 * t + k] = e_w[it][k];
            }
        }
    }
}

// Build flattened (expert, row-block) list: removes all dead blocks from GEMM grids.
__global__ void blocklist_kernel(const int* __restrict__ cnt, int* __restrict__ nblk,
                                 int* __restrict__ be, int* __restrict__ brb) {
    if (threadIdx.x == 0) {
        int nb = 0;
        for (int e = 0; e < E_NUM; ++e) {
            const int nrb = (cnt[e] + 127) >> 7;
            for (int rb = 0; rb < nrb; ++rb) { be[nb] = e; brb[nb] = rb; ++nb; }
        }
        nblk[0] = nb;   // <= 136 < MAXBLK
    }
}

// Gathered bf16 MFMA GEMM (NT), 128x128 tile, BK=32, 4 waves, 16x16x32 MFMA.
// 2-phase double-buffered LDS: stage(t+1) issued before compute(t); ONE
// __syncthreads per K-step (its implicit vmcnt(0)+lgkmcnt(0) drain is the fence).
// Staging: global_load_lds w16, XOR pre-swizzled source + same XOR on ds_read
// (rule #21; measured 0 bank conflicts in round 3).
template<int N, int K, bool FIRST>
__global__ __launch_bounds__(256) void moe_gemm_mfma(
    const ushort* __restrict__ A,    // bf16: FIRST? xb [T,H] : hidden [NSLOT,I]
    const ushort* __restrict__ W,    // bf16 [E,N,K]
    const float* __restrict__ bias,  // fp32 [E,N]
    ushort* __restrict__ OutBf,      // FIRST: hidden [NSLOT,N]
    float* __restrict__ OutAcc,      // !FIRST: out [T,H], atomic accumulate
    const float* __restrict__ gate,  // [NSLOT]
    const int* __restrict__ rowmap,
    const int* __restrict__ cnt,
    const int* __restrict__ nblk,
    const int* __restrict__ blk_e,
    const int* __restrict__ blk_rb)
{
    const int by = blockIdx.y;
    if (by >= nblk[0]) return;
    const int e = blk_e[by];
    const int cnt_e = cnt[e];
    const int row0 = blk_rb[by] * 128;
    const int col0 = blockIdx.x * 128;

    __shared__ int    sslot[128];
    __shared__ ushort lds[2][2][128 * 32];   // [buf][0=A,1=B], 8 KB each

    const int tid = threadIdx.x, lane = tid & 63, w = tid >> 6;
    if (tid < 128) {
        const int r = row0 + tid;
        sslot[tid] = (r < cnt_e) ? rowmap[e * T_TOK + r] : -1;
    }
    __syncthreads();

    // staging addresses: per wave 2 calls per matrix; each covers 16 rows x 32 k.
    const int rsub = lane >> 2;      // row within 16-row call
    const int s4   = lane & 3;       // dest 16B slot within row
    const ushort* gA[2]; const ushort* gB[2];
    int ldoff[2];
#pragma unroll
    for (int c = 0; c < 2; ++c) {
        const int r = (w * 2 + c) * 16 + rsub;       // local row 0..127
        const int g = s4 ^ ((r >> 1) & 3);           // inverse-swizzled source chunk
        int srow = sslot[r]; if (srow < 0) srow = 0;
        const int arow = FIRST ? (srow >> 1) : srow;
        gA[c]  = A + (size_t)arow * K + g * 8;
        gB[c]  = W + ((size_t)e * N + col0 + r) * K + g * 8;
        ldoff[c] = (w * 2 + c) * 512;
    }

    // fragment ds_read offsets (same XOR as source swizzle)
    const int fr = lane & 15;
    const int kq = lane >> 4;
    int offA[4], offB[4];
#pragma unroll
    for (int i = 0; i < 4; ++i) {
        const int r  = (w >> 1) * 64 + i * 16 + fr;
        offA[i] = r * 32 + (kq ^ ((r >> 1) & 3)) * 8;
        const int cr = (w & 1) * 64 + i * 16 + fr;
        offB[i] = cr * 32 + (kq ^ ((cr >> 1) & 3)) * 8;
    }

    f32x4 acc[4][4] = {};

    // prologue: stage K-tile 0 into buf 0
#pragma unroll
    for (int c = 0; c < 2; ++c) {
        gll16(gA[c], &lds[0][0][ldoff[c]]);
        gll16(gB[c], &lds[0][1][ldoff[c]]);
    }
    __syncthreads();

    int cur = 0;
    for (int kt = 32; kt <= K; kt += 32) {   // kt = start of NEXT tile
        if (kt < K) {                        // stage t+1 into the other buffer
#pragma unroll
            for (int c = 0; c < 2; ++c) {
                gll16(gA[c] + kt, &lds[cur ^ 1][0][ldoff[c]]);
                gll16(gB[c] + kt, &lds[cur ^ 1][1][ldoff[c]]);
            }
        }
        bf16x8 af[4], bfr[4];
#pragma unroll
        for (int i = 0; i < 4; ++i) {
            af[i]  = *(const bf16x8*)&lds[cur][0][offA[i]];
            bfr[i] = *(const bf16x8*)&lds[cur][1][offB[i]];
        }
#pragma unroll
        for (int mi = 0; mi < 4; ++mi)
#pragma unroll
            for (int ni = 0; ni < 4; ++ni)
                acc[mi][ni] = __builtin_amdgcn_mfma_f32_16x16x32_bf16(
                    af[mi], bfr[ni], acc[mi][ni], 0, 0, 0);
        __syncthreads();   // all reads of buf[cur] done AND stage(t+1) drained
        cur ^= 1;
    }

    // epilogue. C/D: col = lane&15, row = (lane>>4)*4 + j   [m89-verified]
    const int wrb = (w >> 1) * 64, wcb = (w & 1) * 64;
    float bb[4];
#pragma unroll
    for (int ni = 0; ni < 4; ++ni) bb[ni] = bias[e * N + col0 + wcb + ni * 16 + fr];
    const int rowhi = lane >> 4;
#pragma unroll
    for (int mi = 0; mi < 4; ++mi) {
#pragma unroll
        for (int j = 0; j < 4; ++j) {
            const int r = wrb + mi * 16 + rowhi * 4 + j;
            if (row0 + r < cnt_e) {
                const int slot = sslot[r];
                if (FIRST) {
#pragma unroll
                    for (int ni = 0; ni < 4; ++ni) {
                        const int cg = col0 + wcb + ni * 16 + fr;
                        float v = acc[mi][ni][j] + bb[ni];
                        v = 0.5f * v * (1.0f + erff(v * 0.70710678118654752f));
                        OutBf[(size_t)slot * N + cg] = f2bf(v);
                    }
                } else {
                    const float gw = gate[slot];
                    float* op = OutAcc + (size_t)(slot >> 1) * H_DIM;
#pragma unroll
                    for (int ni = 0; ni < 4; ++ni) {
                        const int cg = col0 + wcb + ni * 16 + fr;
                        atomicAdd(op + cg, gw * (acc[mi][ni][j] + bb[ni]));
                    }
                }
            }
        }
    }
}

__global__ void finalize_kernel(const int* __restrict__ cnt,
                                const float* __restrict__ psum_part,
                                float* __restrict__ out_aux)
{
    __shared__ float P[E_NUM];
    __shared__ float F[E_NUM];
    if (threadIdx.x < E_NUM) {
        float s = 0.0f;
        for (int b = 0; b < ROUTER_BLOCKS; ++b) s += psum_part[b * E_NUM + threadIdx.x];
        P[threadIdx.x] = s / (float)T_TOK;
        F[threadIdx.x] = (float)cnt[threadIdx.x] / (float)(T_TOK * 2);
    }
    __syncthreads();
    if (threadIdx.x == 0) {
        float a = 0.0f;
        for (int e = 0; e < E_NUM; ++e) a += F[e] * P[e];
        out_aux[0] = (float)E_NUM * a;
    }
}

extern "C" void kernel_launch(void* const* d_in, const int* in_sizes, int n_in,
                              void* d_out, int out_size, void* d_ws, size_t ws_size,
                              hipStream_t stream)
{
    const float* x  = (const float*)d_in[0];
    const float* Wr = (const float*)d_in[1];
    const float* W1 = (const float*)d_in[2];
    const float* b1 = (const float*)d_in[3];
    const float* W2 = (const float*)d_in[4];
    const float* b2 = (const float*)d_in[5];
    float* out = (float*)d_out;

    char* ws = (char*)d_ws;
    int*    cnt    = (int*)(ws + OFF_CNT);
    int*    nblk   = (int*)(ws + OFF_NBLK);
    int*    blke   = (int*)(ws + OFF_BLKE);
    int*    blkrb  = (int*)(ws + OFF_BLKRB);
    float*  psum   = (float*)(ws + OFF_PSUM);
    float*  gate   = (float*)(ws + OFF_GATE);
    int*    rowmap = (int*)(ws + OFF_ROWMAP);
    ushort* xb     = (ushort*)(ws + OFF_XB);
    ushort* wb1    = (ushort*)(ws + OFF_WB1);
    ushort* wb2    = (ushort*)(ws + OFF_WB2);
    ushort* hid    = (ushort*)(ws + OFF_HID);

    hipLaunchKernelGGL(init_kernel, dim3(1), dim3(64), 0, stream, cnt);
    hipLaunchKernelGGL(router_kernel, dim3(ROUTER_BLOCKS), dim3(256), 0, stream,
                       x, Wr, cnt, psum, gate, rowmap, xb);
    hipLaunchKernelGGL(blocklist_kernel, dim3(1), dim3(64), 0, stream,
                       cnt, nblk, blke, blkrb);
    hipLaunchKernelGGL(f2bf_kernel, dim3(2048), dim3(256), 0, stream,
                       W1, wb1, E_NUM * I_DIM * H_DIM / 4);
    hipLaunchKernelGGL(f2bf_kernel, dim3(2048), dim3(256), 0, stream,
                       W2, wb2, E_NUM * H_DIM * I_DIM / 4);
    hipLaunchKernelGGL(zero_out_kernel, dim3(T_TOK * H_DIM / 4 / 256), dim3(256), 0, stream,
                       out);
    hipLaunchKernelGGL((moe_gemm_mfma<I_DIM, H_DIM, true>),
                       dim3(I_DIM / 128, MAXBLK), dim3(256), 0, stream,
                       xb, wb1, b1, hid, nullptr, gate, rowmap, cnt, nblk, blke, blkrb);
    hipLaunchKernelGGL((moe_gemm_mfma<H_DIM, I_DIM, false>),
                       dim3(H_DIM / 128, MAXBLK), dim3(256), 0, stream,
                       hid, wb2, b2, nullptr, out, gate, rowmap, cnt, nblk, blke, blkrb);
    hipLaunchKernelGGL(finalize_kernel, dim3(1), dim3(64), 0, stream,
                       cnt, psum, out + (size_t)T_TOK * H_DIM);
}